// Round 5
// baseline (127.852 us; speedup 1.0000x reference)
//
#include <hip/hip_runtime.h>
#include <hip/hip_bf16.h>

typedef float f32x4 __attribute__((ext_vector_type(4)));
typedef short s16x8 __attribute__((ext_vector_type(8)));

#define N_NODES 768
#define NODE_DIM_ 256
#define HDIM 64
#define EDIM 128
#define CTILES 48                       // 768 / 16
#define ATILES_PER_WAVE 12              // 768 a-rows / 64 wave-groups

static __device__ __forceinline__ short f2bf(float f) {
    __hip_bfloat16 h = __float2bfloat16(f);
    return __builtin_bit_cast(short, h);
}

// ---------- Kernel 1: projections, per-row stats, P = N @ (g*W1), S1/C1 ----------
__global__ __launch_bounds__(256) void proj_kernel(
        const float* __restrict__ x,
        const float* __restrict__ Wi, const float* __restrict__ bi,
        const float* __restrict__ Wj, const float* __restrict__ bj,
        const float* __restrict__ W1, const float* __restrict__ b1,
        const float* __restrict__ lng, const float* __restrict__ lnb,
        float* __restrict__ NI, float* __restrict__ NJ,
        float* __restrict__ Pi, float* __restrict__ Pj,
        float* __restrict__ mi, float* __restrict__ qi,
        float* __restrict__ mj, float* __restrict__ qj,
        float* __restrict__ S1, float* __restrict__ C1) {
    __shared__ float W1gL[HDIM * HDIM];   // g[k]*W1[k][n], 16 KB
    __shared__ float rowi[4][HDIM], rowj[4][HDIM];
    for (int idx = threadIdx.x; idx < HDIM * HDIM; idx += 256) {
        int k = idx >> 6;
        W1gL[idx] = lng[k] * W1[idx];
    }

    int wave = threadIdx.x >> 6, lane = threadIdx.x & 63;
    int row  = blockIdx.x * 4 + wave;
    float ai = bi[lane], aj = bj[lane];
    const float* xr = x + row * NODE_DIM_;
#pragma unroll 8
    for (int k = 0; k < NODE_DIM_; ++k) {
        float xv = xr[k];
        ai = fmaf(xv, Wi[k * HDIM + lane], ai);
        aj = fmaf(xv, Wj[k * HDIM + lane], aj);
    }
    NI[row * HDIM + lane] = ai;
    NJ[row * HDIM + lane] = aj;
    rowi[wave][lane] = ai;
    rowj[wave][lane] = aj;

    float si = ai, sqi = ai * ai, sj = aj, sqj = aj * aj;
#pragma unroll
    for (int o = 1; o < 64; o <<= 1) {
        si  += __shfl_xor(si, o);   sqi += __shfl_xor(sqi, o);
        sj  += __shfl_xor(sj, o);   sqj += __shfl_xor(sqj, o);
    }
    if (lane == 0) {
        mi[row] = si * (1.f / 64.f);  qi[row] = sqi * (1.f / 64.f);
        mj[row] = sj * (1.f / 64.f);  qj[row] = sqj * (1.f / 64.f);
    }
    __syncthreads();

    float pi = 0.f, pj = 0.f;
#pragma unroll 8
    for (int k = 0; k < HDIM; ++k) {
        float wg = W1gL[k * HDIM + lane];
        pi = fmaf(rowi[wave][k], wg, pi);
        pj = fmaf(rowj[wave][k], wg, pj);
    }
    Pi[row * HDIM + lane] = pi;
    Pj[row * HDIM + lane] = pj;

    // block 0 additionally produces S1[n] = sum_k g[k]W1[k,n], C1[n] = b@W1 + b1
    if (blockIdx.x == 0 && threadIdx.x < HDIM) {
        int n = threadIdx.x;
        float s = 0.f, cc = 0.f;
#pragma unroll 8
        for (int k = 0; k < HDIM; ++k) {
            s += W1gL[k * HDIM + n];
            cc = fmaf(lnb[k], W1[k * HDIM + n], cc);
        }
        S1[n] = s;
        C1[n] = cc + b1[n];
    }
}

// ---------- Kernel 2: c-fixed wave, stream a; LN folded; GEMM2 + stores (R1 form) ----------
// tf is built directly in A-frag layout: lane holds row c=c0+l15, k = hi*8+j (+32).
__global__ __launch_bounds__(256, 3) void edge_kernel(
        const float* __restrict__ NI, const float* __restrict__ NJ,
        const float* __restrict__ Pi, const float* __restrict__ Pj,
        const float* __restrict__ mi, const float* __restrict__ qi,
        const float* __restrict__ mj, const float* __restrict__ qj,
        const float* __restrict__ S1, const float* __restrict__ C1,
        const float* __restrict__ W2, const float* __restrict__ b2,
        float* __restrict__ out) {
    __shared__ short W2L[8192];  // [(k>>3)][e(128)][k&7] bf16
    for (int idx = threadIdx.x; idx < 8192; idx += 256) {
        int k = idx >> 7, e = idx & 127;
        W2L[(k >> 3) * 1024 + e * 8 + (k & 7)] = f2bf(W2[idx]);
    }
    __syncthreads();

    const int wave = threadIdx.x >> 6;
    const int lane = threadIdx.x & 63;
    const int l15  = lane & 15;
    const int hi   = lane >> 4;

    const int wid     = blockIdx.x * 4 + wave;      // 0..3071
    const int c0      = (wid % CTILES) * 16;
    const int a_start = wid / CTILES;               // 0..63
    const int c       = c0 + l15;

    // ---- loop-invariant, register-resident ----
    const float* nip = NI + c * HDIM + hi * 8;
    f32x4 vi0 = *(const f32x4*)nip;
    f32x4 vi1 = *(const f32x4*)(nip + 4);
    f32x4 vi2 = *(const f32x4*)(nip + 32);
    f32x4 vi3 = *(const f32x4*)(nip + 36);
    const float* pip = Pi + c * HDIM + hi * 8;
    f32x4 pia = *(const f32x4*)pip;
    f32x4 pib = *(const f32x4*)(pip + 4);
    f32x4 pic = *(const f32x4*)(pip + 32);
    f32x4 pid = *(const f32x4*)(pip + 36);
    const float mic = mi[c], qic = qi[c];
    f32x4 S1a = *(const f32x4*)&S1[hi * 8];
    f32x4 S1b = *(const f32x4*)&S1[hi * 8 + 4];
    f32x4 S1c = *(const f32x4*)&S1[32 + hi * 8];
    f32x4 S1d = *(const f32x4*)&S1[32 + hi * 8 + 4];
    f32x4 C1a = *(const f32x4*)&C1[hi * 8];
    f32x4 C1b = *(const f32x4*)&C1[hi * 8 + 4];
    f32x4 C1c = *(const f32x4*)&C1[32 + hi * 8];
    f32x4 C1d = *(const f32x4*)&C1[32 + hi * 8 + 4];
    float b2v[8];
#pragma unroll
    for (int nt = 0; nt < 8; ++nt)
        b2v[nt] = b2[nt * 16 + l15];

#pragma unroll 2
    for (int ai = 0; ai < ATILES_PER_WAVE; ++ai) {
        const int a = a_start + ai * 64;

        // per-iteration loads: NJ row + Pj row (256 B each) + 2 scalars
        const float* njp = NJ + a * HDIM + hi * 8;
        f32x4 nj0 = *(const f32x4*)njp;
        f32x4 nj1 = *(const f32x4*)(njp + 4);
        f32x4 nj2 = *(const f32x4*)(njp + 32);
        f32x4 nj3 = *(const f32x4*)(njp + 36);
        const float* pjp = Pj + a * HDIM + hi * 8;
        f32x4 pj0 = *(const f32x4*)pjp;
        f32x4 pj1 = *(const f32x4*)(pjp + 4);
        f32x4 pj2 = *(const f32x4*)(pjp + 32);
        f32x4 pj3 = *(const f32x4*)(pjp + 36);
        const float mja = mj[a], qja = qj[a];

        // cross dot(ni, nj): per-lane 16 FMA + 2 shuffles
        float d = 0.f;
#pragma unroll
        for (int j = 0; j < 4; ++j) {
            d = fmaf(vi0[j], nj0[j], d);
            d = fmaf(vi1[j], nj1[j], d);
            d = fmaf(vi2[j], nj2[j], d);
            d = fmaf(vi3[j], nj3[j], d);
        }
        d += __shfl_xor(d, 16);
        d += __shfl_xor(d, 32);

        const float mu   = mic + mja;
        const float var  = qic + qja + d * (1.f / 32.f) - mu * mu;
        const float rstd = rsqrtf(var + 1e-5f);
        const float rm   = rstd * mu;

        // t = relu(rstd*(Pi+Pj) - rm*S1 + C1), straight into A-frag layout
        s16x8 tf0, tf1;
#pragma unroll
        for (int j = 0; j < 4; ++j) {
            float t0 = fmaf(rstd, pia[j] + pj0[j], fmaf(-rm, S1a[j], C1a[j]));
            float t1 = fmaf(rstd, pib[j] + pj1[j], fmaf(-rm, S1b[j], C1b[j]));
            float t2 = fmaf(rstd, pic[j] + pj2[j], fmaf(-rm, S1c[j], C1c[j]));
            float t3 = fmaf(rstd, pid[j] + pj3[j], fmaf(-rm, S1d[j], C1d[j]));
            tf0[j]     = f2bf(fmaxf(t0, 0.f));
            tf0[4 + j] = f2bf(fmaxf(t1, 0.f));
            tf1[j]     = f2bf(fmaxf(t2, 0.f));
            tf1[4 + j] = f2bf(fmaxf(t3, 0.f));
        }

        // GEMM2 (R1 form): D rows = c-dim (c0+hi*4+r), cols = e (nt*16+l15)
        float* op = out + ((size_t)(a * N_NODES + c0 + hi * 4)) * EDIM + l15;
#pragma unroll
        for (int nt = 0; nt < 8; ++nt) {
            f32x4 acc = {0.f, 0.f, 0.f, 0.f};
            s16x8 w0 = *(const s16x8*)&W2L[(0 + hi) * 1024 + (nt * 16 + l15) * 8];
            s16x8 w1 = *(const s16x8*)&W2L[(4 + hi) * 1024 + (nt * 16 + l15) * 8];
            acc = __builtin_amdgcn_mfma_f32_16x16x32_bf16(tf0, w0, acc, 0, 0, 0);
            acc = __builtin_amdgcn_mfma_f32_16x16x32_bf16(tf1, w1, acc, 0, 0, 0);
#pragma unroll
            for (int r = 0; r < 4; ++r)
                op[(size_t)r * EDIM + nt * 16] = acc[r] + b2v[nt];
        }
    }
}

extern "C" void kernel_launch(void* const* d_in, const int* in_sizes, int n_in,
                              void* d_out, int out_size, void* d_ws, size_t ws_size,
                              hipStream_t stream) {
    const float* x   = (const float*)d_in[0];
    const float* Wi  = (const float*)d_in[2];
    const float* bi  = (const float*)d_in[3];
    const float* Wj  = (const float*)d_in[4];
    const float* bj  = (const float*)d_in[5];
    const float* lng = (const float*)d_in[6];
    const float* lnb = (const float*)d_in[7];
    const float* W1  = (const float*)d_in[8];
    const float* b1  = (const float*)d_in[9];
    const float* W2  = (const float*)d_in[10];
    const float* b2  = (const float*)d_in[11];
    float* out = (float*)d_out;

    // workspace layout (floats): ~205k floats = 820 KB
    float* ws = (float*)d_ws;
    float* NI = ws;                    // 49152
    float* NJ = NI + 49152;            // 49152
    float* Pi = NJ + 49152;            // 49152
    float* Pj = Pi + 49152;            // 49152
    float* mi = Pj + 49152;            // 768
    float* qi = mi + 768;              // 768
    float* mj = qi + 768;              // 768
    float* qj = mj + 768;              // 768
    float* S1 = qj + 768;              // 64
    float* C1 = S1 + 64;               // 64

    proj_kernel<<<N_NODES / 4, 256, 0, stream>>>(x, Wi, bi, Wj, bj, W1, b1, lng, lnb,
                                                 NI, NJ, Pi, Pj, mi, qi, mj, qj, S1, C1);
    edge_kernel<<<768, 256, 0, stream>>>(NI, NJ, Pi, Pj, mi, qi, mj, qj,
                                         S1, C1, W2, b2, out);
}

// Round 6
// 96.402 us; speedup vs baseline: 1.3262x; 1.3262x over previous
//
#include <hip/hip_runtime.h>
#include <hip/hip_bf16.h>

typedef float f32x4 __attribute__((ext_vector_type(4)));
typedef short s16x8 __attribute__((ext_vector_type(8)));

#define N_NODES 768
#define NODE_DIM_ 256
#define HDIM 64
#define EDIM 128
#define CTILES 48                       // 768 / 16
#define TILES_TOTAL (N_NODES * CTILES)  // 36864

static __device__ __forceinline__ short f2bf(float f) {
    __hip_bfloat16 h = __float2bfloat16(f);
    return __builtin_bit_cast(short, h);
}

// ---------- Kernel 1: projections, per-row stats, P = N @ (g*W1), S1/C1 ----------
__global__ __launch_bounds__(256) void proj_kernel(
        const float* __restrict__ x,
        const float* __restrict__ Wi, const float* __restrict__ bi,
        const float* __restrict__ Wj, const float* __restrict__ bj,
        const float* __restrict__ W1, const float* __restrict__ b1,
        const float* __restrict__ lng, const float* __restrict__ lnb,
        float* __restrict__ NI, float* __restrict__ NJ,
        float* __restrict__ Pi, float* __restrict__ Pj,
        float* __restrict__ mi, float* __restrict__ qi,
        float* __restrict__ mj, float* __restrict__ qj,
        float* __restrict__ S1, float* __restrict__ C1) {
    __shared__ float W1gL[HDIM * HDIM];   // g[k]*W1[k][n], 16 KB
    __shared__ float rowi[4][HDIM], rowj[4][HDIM];
    for (int idx = threadIdx.x; idx < HDIM * HDIM; idx += 256) {
        int k = idx >> 6;
        W1gL[idx] = lng[k] * W1[idx];
    }

    int wave = threadIdx.x >> 6, lane = threadIdx.x & 63;
    int row  = blockIdx.x * 4 + wave;
    float ai = bi[lane], aj = bj[lane];
    const float* xr = x + row * NODE_DIM_;
#pragma unroll 8
    for (int k = 0; k < NODE_DIM_; ++k) {
        float xv = xr[k];
        ai = fmaf(xv, Wi[k * HDIM + lane], ai);
        aj = fmaf(xv, Wj[k * HDIM + lane], aj);
    }
    NI[row * HDIM + lane] = ai;
    NJ[row * HDIM + lane] = aj;
    rowi[wave][lane] = ai;
    rowj[wave][lane] = aj;

    float si = ai, sqi = ai * ai, sj = aj, sqj = aj * aj;
#pragma unroll
    for (int o = 1; o < 64; o <<= 1) {
        si  += __shfl_xor(si, o);   sqi += __shfl_xor(sqi, o);
        sj  += __shfl_xor(sj, o);   sqj += __shfl_xor(sqj, o);
    }
    if (lane == 0) {
        mi[row] = si * (1.f / 64.f);  qi[row] = sqi * (1.f / 64.f);
        mj[row] = sj * (1.f / 64.f);  qj[row] = sqj * (1.f / 64.f);
    }
    __syncthreads();

    float pi = 0.f, pj = 0.f;
#pragma unroll 8
    for (int k = 0; k < HDIM; ++k) {
        float wg = W1gL[k * HDIM + lane];
        pi = fmaf(rowi[wave][k], wg, pi);
        pj = fmaf(rowj[wave][k], wg, pj);
    }
    Pi[row * HDIM + lane] = pi;
    Pj[row * HDIM + lane] = pj;

    if (blockIdx.x == 0 && threadIdx.x < HDIM) {
        int n = threadIdx.x;
        float s = 0.f, cc = 0.f;
#pragma unroll 8
        for (int k = 0; k < HDIM; ++k) {
            s += W1gL[k * HDIM + n];
            cc = fmaf(lnb[k], W1[k * HDIM + n], cc);
        }
        S1[n] = s;
        C1[n] = cc + b1[n];
    }
}

// ---------- Kernel 2: folded-LN per-pair t; GEMM2; full-line stores via LDS ----------
// R1 frame: 2304 blocks, grid-stride, 4 tiles/wave. Swapped GEMM2 acc
// (lane -> out[c=c0+l15][e=nt*16+hi*4+r]) goes through a per-wave swizzled
// LDS tile so each global store writes full 128B lines (no partial-line RMW).
__global__ __launch_bounds__(256) void edge_kernel(
        const float* __restrict__ NI, const float* __restrict__ NJ,
        const float* __restrict__ Pi, const float* __restrict__ Pj,
        const float* __restrict__ mi, const float* __restrict__ qi,
        const float* __restrict__ mj, const float* __restrict__ qj,
        const float* __restrict__ S1, const float* __restrict__ C1,
        const float* __restrict__ W2, const float* __restrict__ b2,
        float* __restrict__ out) {
    __shared__ short W2L[8192];     // [(k>>3)][e(128)][k&7] bf16, 16 KB
    __shared__ float OT[4][1024];   // per-wave 16x64 f32 half-tile, 4 KB/wave

    for (int idx = threadIdx.x; idx < 8192; idx += 256) {
        int k = idx >> 7, e = idx & 127;
        W2L[(k >> 3) * 1024 + e * 8 + (k & 7)] = f2bf(W2[idx]);
    }
    __syncthreads();

    const int wave = threadIdx.x >> 6;
    const int lane = threadIdx.x & 63;
    const int l15  = lane & 15;
    const int hi   = lane >> 4;

    // invariants (lean): S1/C1 frags (32 regs) + 2 bias vectors (8 regs)
    f32x4 S1a = *(const f32x4*)&S1[hi * 8];
    f32x4 S1b = *(const f32x4*)&S1[hi * 8 + 4];
    f32x4 S1c = *(const f32x4*)&S1[32 + hi * 8];
    f32x4 S1d = *(const f32x4*)&S1[32 + hi * 8 + 4];
    f32x4 C1a = *(const f32x4*)&C1[hi * 8];
    f32x4 C1b = *(const f32x4*)&C1[hi * 8 + 4];
    f32x4 C1c = *(const f32x4*)&C1[32 + hi * 8];
    f32x4 C1d = *(const f32x4*)&C1[32 + hi * 8 + 4];
    f32x4 b2h0 = *(const f32x4*)&b2[l15 * 4];        // store cols eh=0: l15*4..+3
    f32x4 b2h1 = *(const f32x4*)&b2[64 + l15 * 4];   // store cols eh=1

    char* ot = (char*)&OT[wave][0];

    const int wid = blockIdx.x * 4 + wave;
    const int nw  = gridDim.x * 4;
    for (int t = wid; t < TILES_TOTAL; t += nw) {
        const int a  = t / CTILES;
        const int c0 = (t - a * CTILES) * 16;
        const int c  = c0 + l15;

        // per-tile loads (all L2-resident): rows of NI/Pi (per-l15) and NJ/Pj (uniform)
        const float* nip = NI + c * HDIM + hi * 8;
        const float* njp = NJ + a * HDIM + hi * 8;
        const float* pip = Pi + c * HDIM + hi * 8;
        const float* pjp = Pj + a * HDIM + hi * 8;
        f32x4 ni0 = *(const f32x4*)nip;
        f32x4 ni1 = *(const f32x4*)(nip + 4);
        f32x4 ni2 = *(const f32x4*)(nip + 32);
        f32x4 ni3 = *(const f32x4*)(nip + 36);
        f32x4 nj0 = *(const f32x4*)njp;
        f32x4 nj1 = *(const f32x4*)(njp + 4);
        f32x4 nj2 = *(const f32x4*)(njp + 32);
        f32x4 nj3 = *(const f32x4*)(njp + 36);
        f32x4 pi0 = *(const f32x4*)pip;
        f32x4 pi1 = *(const f32x4*)(pip + 4);
        f32x4 pi2 = *(const f32x4*)(pip + 32);
        f32x4 pi3 = *(const f32x4*)(pip + 36);
        f32x4 pj0 = *(const f32x4*)pjp;
        f32x4 pj1 = *(const f32x4*)(pjp + 4);
        f32x4 pj2 = *(const f32x4*)(pjp + 32);
        f32x4 pj3 = *(const f32x4*)(pjp + 36);
        const float mic = mi[c], qic = qi[c];
        const float mja = mj[a], qja = qj[a];

        // cross dot(ni, nj): 16 FMA + 2 shuffles (hi groups partition k)
        float d = 0.f;
#pragma unroll
        for (int j = 0; j < 4; ++j) {
            d = fmaf(ni0[j], nj0[j], d);
            d = fmaf(ni1[j], nj1[j], d);
            d = fmaf(ni2[j], nj2[j], d);
            d = fmaf(ni3[j], nj3[j], d);
        }
        d += __shfl_xor(d, 16);
        d += __shfl_xor(d, 32);

        const float mu   = mic + mja;
        const float var  = qic + qja + d * (1.f / 32.f) - mu * mu;
        const float rstd = rsqrtf(var + 1e-5f);
        const float rm   = rstd * mu;

        // t = relu(rstd*(Pi+Pj) - rm*S1 + C1), built directly in frag layout
        s16x8 tf0, tf1;
#pragma unroll
        for (int j = 0; j < 4; ++j) {
            float t0 = fmaf(rstd, pi0[j] + pj0[j], fmaf(-rm, S1a[j], C1a[j]));
            float t1 = fmaf(rstd, pi1[j] + pj1[j], fmaf(-rm, S1b[j], C1b[j]));
            float t2 = fmaf(rstd, pi2[j] + pj2[j], fmaf(-rm, S1c[j], C1c[j]));
            float t3 = fmaf(rstd, pi3[j] + pj3[j], fmaf(-rm, S1d[j], C1d[j]));
            tf0[j]     = f2bf(fmaxf(t0, 0.f));
            tf0[4 + j] = f2bf(fmaxf(t1, 0.f));
            tf1[j]     = f2bf(fmaxf(t2, 0.f));
            tf1[4 + j] = f2bf(fmaxf(t3, 0.f));
        }

        // GEMM2 swapped, e-halves of 64 cols; acc -> swizzled LDS -> full-line stores
#pragma unroll
        for (int eh = 0; eh < 2; ++eh) {
#pragma unroll
            for (int nt2 = 0; nt2 < 4; ++nt2) {
                const int nt = eh * 4 + nt2;
                f32x4 acc = {0.f, 0.f, 0.f, 0.f};
                s16x8 w0 = *(const s16x8*)&W2L[(0 + hi) * 1024 + (nt * 16 + l15) * 8];
                s16x8 w1 = *(const s16x8*)&W2L[(4 + hi) * 1024 + (nt * 16 + l15) * 8];
                acc = __builtin_amdgcn_mfma_f32_16x16x32_bf16(w0, tf0, acc, 0, 0, 0);
                acc = __builtin_amdgcn_mfma_f32_16x16x32_bf16(w1, tf1, acc, 0, 0, 0);
                // row = l15 (c), cols nt2*16+hi*4..+3 of the half
                int wb = (l15 * 256 + nt2 * 64 + hi * 16) ^ ((l15 & 7) << 4);
                *(f32x4*)(ot + wb) = acc;
            }
            f32x4 bb = eh ? b2h1 : b2h0;
            // read back row-contiguous: instr i covers rows i*4+hi, cols l15*4..+3
#pragma unroll
            for (int i = 0; i < 4; ++i) {
                const int r = i * 4 + hi;
                int rb = (r * 256 + l15 * 16) ^ ((r & 7) << 4);
                f32x4 v = *(const f32x4*)(ot + rb);
                v += bb;
                *(f32x4*)(out + ((size_t)(a * N_NODES + c0 + r)) * EDIM + eh * 64 + l15 * 4) = v;
            }
        }
    }
}

extern "C" void kernel_launch(void* const* d_in, const int* in_sizes, int n_in,
                              void* d_out, int out_size, void* d_ws, size_t ws_size,
                              hipStream_t stream) {
    const float* x   = (const float*)d_in[0];
    const float* Wi  = (const float*)d_in[2];
    const float* bi  = (const float*)d_in[3];
    const float* Wj  = (const float*)d_in[4];
    const float* bj  = (const float*)d_in[5];
    const float* lng = (const float*)d_in[6];
    const float* lnb = (const float*)d_in[7];
    const float* W1  = (const float*)d_in[8];
    const float* b1  = (const float*)d_in[9];
    const float* W2  = (const float*)d_in[10];
    const float* b2  = (const float*)d_in[11];
    float* out = (float*)d_out;

    float* ws = (float*)d_ws;
    float* NI = ws;                    // 49152
    float* NJ = NI + 49152;            // 49152
    float* Pi = NJ + 49152;            // 49152
    float* Pj = Pi + 49152;            // 49152
    float* mi = Pj + 49152;            // 768
    float* qi = mi + 768;              // 768
    float* mj = qi + 768;              // 768
    float* qj = mj + 768;              // 768
    float* S1 = qj + 768;              // 64
    float* C1 = S1 + 64;               // 64

    proj_kernel<<<N_NODES / 4, 256, 0, stream>>>(x, Wi, bi, Wj, bj, W1, b1, lng, lnb,
                                                 NI, NJ, Pi, Pj, mi, qi, mj, qj, S1, C1);
    edge_kernel<<<2304, 256, 0, stream>>>(NI, NJ, Pi, Pj, mi, qi, mj, qj,
                                          S1, C1, W2, b2, out);
}

// Round 8
// 89.796 us; speedup vs baseline: 1.4238x; 1.0736x over previous
//
#include <hip/hip_runtime.h>
#include <hip/hip_bf16.h>

typedef float f32x4 __attribute__((ext_vector_type(4)));
typedef short s16x8 __attribute__((ext_vector_type(8)));
typedef short s16x4 __attribute__((ext_vector_type(4)));

#define N_NODES 768
#define NODE_DIM_ 256
#define HDIM 64
#define EDIM 128
#define CTILES 48                       // 768 / 16
#define TILES_TOTAL (N_NODES * CTILES)  // 36864

static __device__ __forceinline__ short f2bf(float f) {
    __hip_bfloat16 h = __float2bfloat16(f);
    return __builtin_bit_cast(short, h);
}
static __device__ __forceinline__ float bf2f(short h) {
    unsigned u = ((unsigned)(unsigned short)h) << 16;
    return __builtin_bit_cast(float, u);
}

// ---------------- Kernel 1: n_i = x@Wi + bi, n_j = x@Wj + bj ----------------
__global__ __launch_bounds__(256) void proj_kernel(
        const float* __restrict__ x,
        const float* __restrict__ Wi, const float* __restrict__ bi,
        const float* __restrict__ Wj, const float* __restrict__ bj,
        float* __restrict__ NI, float* __restrict__ NJ) {
    int row  = blockIdx.x * 4 + (threadIdx.x >> 6);
    int lane = threadIdx.x & 63;
    float ai = bi[lane];
    float aj = bj[lane];
    const float* xr = x + row * NODE_DIM_;
#pragma unroll 8
    for (int k = 0; k < NODE_DIM_; ++k) {
        float xv = xr[k];
        ai = fmaf(xv, Wi[k * HDIM + lane], ai);
        aj = fmaf(xv, Wj[k * HDIM + lane], aj);
    }
    NI[row * HDIM + lane] = ai;
    NJ[row * HDIM + lane] = aj;
}

// ------- Kernel 2: LN -> GEMM1(relu) -> GEMM2, split-bf16 activations -------
// h and t are carried as (hi, lo) bf16 pairs -> activation path is fp32-accurate;
// residual error is only W1/W2 bf16 rounding (~2e-3, robust to build variance).
// Blocked tile assignment: wave owns 4 consecutive tiles (32KB sequential writes);
// bijective XCD swizzle puts contiguous output slabs on each XCD.
__global__ __launch_bounds__(256) void edge_kernel(
        const float* __restrict__ NI, const float* __restrict__ NJ,
        const float* __restrict__ lng, const float* __restrict__ lnb,
        const float* __restrict__ W1, const float* __restrict__ b1,
        const float* __restrict__ W2, const float* __restrict__ b2,
        float* __restrict__ out) {
    __shared__ short W1L[4096];      // [(kh*4+hi)][n(64)][j(8)]  bf16, 8 KB
    __shared__ short W2L[8192];      // [(kh*4+hi)][n(128)][j(8)] bf16, 16 KB
    __shared__ short TLh[4][1024];   // per-wave t-hi tile [16][64] bf16, swizzled
    __shared__ short TLl[4][1024];   // per-wave t-lo tile

    for (int idx = threadIdx.x; idx < 4096; idx += 256) {
        int k = idx >> 6, n = idx & 63;
        W1L[(k >> 3) * 512 + n * 8 + (k & 7)] = f2bf(W1[idx]);
    }
    for (int idx = threadIdx.x; idx < 8192; idx += 256) {
        int k = idx >> 7, n = idx & 127;
        W2L[(k >> 3) * 1024 + n * 8 + (k & 7)] = f2bf(W2[idx]);
    }
    __syncthreads();

    const int wave = threadIdx.x >> 6;
    const int lane = threadIdx.x & 63;
    const int l15  = lane & 15;
    const int hi   = lane >> 4;
    const int swz  = (l15 & 7) << 4;

    float gl[8], gh[8], bl[8], bh[8];
#pragma unroll
    for (int j = 0; j < 8; ++j) {
        gl[j] = lng[hi * 8 + j];      gh[j] = lng[32 + hi * 8 + j];
        bl[j] = lnb[hi * 8 + j];      bh[j] = lnb[32 + hi * 8 + j];
    }
    float b1v[16];
#pragma unroll
    for (int nt = 0; nt < 4; ++nt)
#pragma unroll
        for (int r = 0; r < 4; ++r)
            b1v[nt * 4 + r] = b1[nt * 16 + hi * 4 + r];
    float b2v[8];
#pragma unroll
    for (int nt = 0; nt < 8; ++nt)
        b2v[nt] = b2[nt * 16 + l15];

    char* tlh = (char*)&TLh[wave][0];
    char* tll = (char*)&TLl[wave][0];

    // Bijective XCD swizzle: 2304 = 8 * 288.
    const int swzb = (blockIdx.x & 7) * 288 + (blockIdx.x >> 3);
    const int wid  = swzb * 4 + wave;
    const int t0   = wid * 4;        // 4 consecutive tiles -> 32KB sequential writes

#pragma unroll 1
    for (int k4 = 0; k4 < 4; ++k4) {
        const int t  = t0 + k4;
        const int a  = t / CTILES;
        const int c0 = (t - a * CTILES) * 16;

        const float* nip = NI + (c0 + l15) * HDIM + hi * 8;
        const float* njp = NJ + a * HDIM + hi * 8;
        float v[16];
#pragma unroll
        for (int j = 0; j < 8; ++j) {
            v[j]     = nip[j]      + njp[j];
            v[8 + j] = nip[32 + j] + njp[32 + j];
        }
        float s = 0.f, ss = 0.f;
#pragma unroll
        for (int j = 0; j < 16; ++j) { s += v[j]; ss = fmaf(v[j], v[j], ss); }
        s += __shfl_xor(s, 16);  ss += __shfl_xor(ss, 16);
        s += __shfl_xor(s, 32);  ss += __shfl_xor(ss, 32);
        float mu   = s * (1.f / 64.f);
        float var  = ss * (1.f / 64.f) - mu * mu;
        float rstd = rsqrtf(var + 1e-5f);

        // h fragments, split into hi+lo bf16 (activation fp32-accurate)
        s16x8 hf0h, hf0l, hf1h, hf1l;
#pragma unroll
        for (int j = 0; j < 8; ++j) {
            float h0 = fmaf((v[j]     - mu) * rstd, gl[j], bl[j]);
            float h1 = fmaf((v[8 + j] - mu) * rstd, gh[j], bh[j]);
            short a0 = f2bf(h0);
            short a1 = f2bf(h1);
            hf0h[j] = a0;  hf0l[j] = f2bf(h0 - bf2f(a0));
            hf1h[j] = a1;  hf1l[j] = f2bf(h1 - bf2f(a1));
        }

        // GEMM1 (swapped): 4 MFMA per nt (hi+lo over both k-halves)
#pragma unroll
        for (int nt = 0; nt < 4; ++nt) {
            f32x4 acc = {0.f, 0.f, 0.f, 0.f};
            s16x8 w0 = *(const s16x8*)&W1L[(0 + hi) * 512 + (nt * 16 + l15) * 8];
            s16x8 w1 = *(const s16x8*)&W1L[(4 + hi) * 512 + (nt * 16 + l15) * 8];
            acc = __builtin_amdgcn_mfma_f32_16x16x32_bf16(w0, hf0h, acc, 0, 0, 0);
            acc = __builtin_amdgcn_mfma_f32_16x16x32_bf16(w1, hf1h, acc, 0, 0, 0);
            acc = __builtin_amdgcn_mfma_f32_16x16x32_bf16(w0, hf0l, acc, 0, 0, 0);
            acc = __builtin_amdgcn_mfma_f32_16x16x32_bf16(w1, hf1l, acc, 0, 0, 0);
            s16x4 tvh, tvl;
#pragma unroll
            for (int r = 0; r < 4; ++r) {
                float tt = fmaxf(acc[r] + b1v[nt * 4 + r], 0.f);
                short th = f2bf(tt);
                tvh[r] = th;
                tvl[r] = f2bf(tt - bf2f(th));
            }
            int wb = (l15 * 128 + (nt * 16 + hi * 4) * 2) ^ swz;
            *(s16x4*)(tlh + wb) = tvh;
            *(s16x4*)(tll + wb) = tvl;
        }

        int rb0 = (l15 * 128 + hi * 16) ^ swz;
        int rb1 = (l15 * 128 + hi * 16 + 64) ^ swz;
        s16x8 tf0h = *(const s16x8*)(tlh + rb0);
        s16x8 tf1h = *(const s16x8*)(tlh + rb1);
        s16x8 tf0l = *(const s16x8*)(tll + rb0);
        s16x8 tf1l = *(const s16x8*)(tll + rb1);

        // GEMM2: 4 MFMA per nt (hi+lo)
        float* op = out + ((size_t)(a * N_NODES + c0 + hi * 4)) * EDIM + l15;
#pragma unroll
        for (int nt = 0; nt < 8; ++nt) {
            f32x4 acc = {0.f, 0.f, 0.f, 0.f};
            s16x8 w0 = *(const s16x8*)&W2L[(0 + hi) * 1024 + (nt * 16 + l15) * 8];
            s16x8 w1 = *(const s16x8*)&W2L[(4 + hi) * 1024 + (nt * 16 + l15) * 8];
            acc = __builtin_amdgcn_mfma_f32_16x16x32_bf16(tf0h, w0, acc, 0, 0, 0);
            acc = __builtin_amdgcn_mfma_f32_16x16x32_bf16(tf1h, w1, acc, 0, 0, 0);
            acc = __builtin_amdgcn_mfma_f32_16x16x32_bf16(tf0l, w0, acc, 0, 0, 0);
            acc = __builtin_amdgcn_mfma_f32_16x16x32_bf16(tf1l, w1, acc, 0, 0, 0);
#pragma unroll
            for (int r = 0; r < 4; ++r)
                op[(size_t)r * EDIM + nt * 16] = acc[r] + b2v[nt];
        }
    }
}

extern "C" void kernel_launch(void* const* d_in, const int* in_sizes, int n_in,
                              void* d_out, int out_size, void* d_ws, size_t ws_size,
                              hipStream_t stream) {
    const float* x   = (const float*)d_in[0];
    const float* Wi  = (const float*)d_in[2];
    const float* bi  = (const float*)d_in[3];
    const float* Wj  = (const float*)d_in[4];
    const float* bj  = (const float*)d_in[5];
    const float* lng = (const float*)d_in[6];
    const float* lnb = (const float*)d_in[7];
    const float* W1  = (const float*)d_in[8];
    const float* b1  = (const float*)d_in[9];
    const float* W2  = (const float*)d_in[10];
    const float* b2  = (const float*)d_in[11];
    float* out = (float*)d_out;

    float* NI = (float*)d_ws;
    float* NJ = NI + N_NODES * HDIM;

    proj_kernel<<<N_NODES / 4, 256, 0, stream>>>(x, Wi, bi, Wj, bj, NI, NJ);
    edge_kernel<<<2304, 256, 0, stream>>>(NI, NJ, lng, lnb, W1, b1, W2, b2, out);
}